// Round 1
// baseline (316.505 us; speedup 1.0000x reference)
//
#include <hip/hip_runtime.h>

// Problem: N=32, W=64, H=64, C=256, D_STYLE=256. All fp32 in/out.
// out = leaky0.1( (inputs * softmax_c(colsum*q*s) * softmax_wh(inputs·q*s)) @ Wconv )
// Restructure: ca folded into weights (diag(ca)@W), inputs pre-cast to bf16 in the
// reduce pass, conv uses global_load_lds with XOR-swizzled sources, BN=256.

#define NBATCH 32
#define PIX 4096          // 64*64
#define CH 256
#define SCALE 0.0625f     // 1/sqrt(256)

typedef __attribute__((ext_vector_type(8))) short short8;
typedef __attribute__((ext_vector_type(4))) short short4v;
typedef __attribute__((ext_vector_type(4))) float floatx4;

__device__ __forceinline__ short f2bf(float x) {
    unsigned u = __builtin_bit_cast(unsigned, x);
    u += 0x7fffu + ((u >> 16) & 1u);   // round-to-nearest-even
    return (short)(u >> 16);
}

// async global->LDS, 16B per lane; LDS dest = wave-uniform base + lane*16
__device__ __forceinline__ void gll16(const void* g, void* l) {
    __builtin_amdgcn_global_load_lds(
        (const __attribute__((address_space(1))) unsigned int*)g,
        (__attribute__((address_space(3))) unsigned int*)l, 16, 0, 0);
}

// ---------------- K1: q = leaky_relu(style @ w_dense, 0.3) -------------------
__global__ __launch_bounds__(256) void style_kernel(
    const float* __restrict__ style, const float* __restrict__ wd,
    float* __restrict__ q)
{
    __shared__ float s[256];
    const int n = blockIdx.x, t = threadIdx.x;
    s[t] = style[n * 256 + t];
    __syncthreads();
    float acc = 0.f;
#pragma unroll 8
    for (int k = 0; k < 256; ++k) acc += s[k] * wd[k * 256 + t];
    q[n * 256 + t] = acc > 0.f ? acc : 0.3f * acc;
}

// ---------------- K2: pa_logits + colsum partials + bf16 cast of inputs ------
__global__ __launch_bounds__(256) void reduce_cast_kernel(
    const float* __restrict__ inp, const float* __restrict__ q,
    float* __restrict__ colsum_part, float* __restrict__ pa_logits,
    short* __restrict__ bf16in)
{
    const int n = blockIdx.y;
    const int chunk = blockIdx.x;        // 32 chunks of 128 pixels
    const int lane = threadIdx.x & 63, w = threadIdx.x >> 6;
    const float4 qv = *(const float4*)&q[n * 256 + lane * 4];
    float4 cs = make_float4(0.f, 0.f, 0.f, 0.f);
    const int pbase = chunk * 128 + w * 32;
    const float* base = inp + ((size_t)n * PIX + pbase) * CH;
    short* obase = bf16in + ((size_t)n * PIX + pbase) * CH;
    for (int j = 0; j < 32; ++j) {
        float4 v = *(const float4*)&base[(size_t)j * CH + lane * 4];
        float d = v.x * qv.x + v.y * qv.y + v.z * qv.z + v.w * qv.w;
        cs.x += v.x; cs.y += v.y; cs.z += v.z; cs.w += v.w;
        short4v sv;
        sv.x = f2bf(v.x); sv.y = f2bf(v.y); sv.z = f2bf(v.z); sv.w = f2bf(v.w);
        *(short4v*)&obase[(size_t)j * CH + lane * 4] = sv;
#pragma unroll
        for (int off = 32; off; off >>= 1) d += __shfl_xor(d, off);
        if (lane == 0) pa_logits[n * PIX + pbase + j] = d * SCALE;
    }
    // one partial row per wave; no atomics, no zero-init needed
    *(float4*)&colsum_part[((size_t)n * 128 + chunk * 4 + w) * 256 + lane * 4] = cs;
}

// ---------------- K3: ca = softmax_c(colsum*q*s); pa = softmax_p(pa_logits) --
__global__ __launch_bounds__(256) void softmax_kernel(
    const float* __restrict__ colsum_part, const float* __restrict__ q,
    const float* __restrict__ pa_logits,
    float* __restrict__ ca, float* __restrict__ pa)
{
    __shared__ float red[256];
    const int n = blockIdx.x, t = threadIdx.x;

    // ---- ca over 256 channels ----
    float csum = 0.f;
#pragma unroll 8
    for (int i = 0; i < 128; ++i) csum += colsum_part[((size_t)n * 128 + i) * 256 + t];
    float lg = csum * q[n * 256 + t] * SCALE;
    red[t] = lg; __syncthreads();
    for (int s = 128; s > 0; s >>= 1) {
        if (t < s) red[t] = fmaxf(red[t], red[t + s]);
        __syncthreads();
    }
    float m = red[0]; __syncthreads();
    float e = expf(lg - m);
    red[t] = e; __syncthreads();
    for (int s = 128; s > 0; s >>= 1) {
        if (t < s) red[t] += red[t + s];
        __syncthreads();
    }
    ca[n * 256 + t] = e / red[0];
    __syncthreads();

    // ---- pa over 4096 pixels ----
    float lv[16];
    float lmax = -1e30f;
#pragma unroll
    for (int i = 0; i < 16; ++i) {
        lv[i] = pa_logits[n * PIX + t + 256 * i];
        lmax = fmaxf(lmax, lv[i]);
    }
    red[t] = lmax; __syncthreads();
    for (int s = 128; s > 0; s >>= 1) {
        if (t < s) red[t] = fmaxf(red[t], red[t + s]);
        __syncthreads();
    }
    float M = red[0]; __syncthreads();
    float ev[16], lsum = 0.f;
#pragma unroll
    for (int i = 0; i < 16; ++i) { ev[i] = expf(lv[i] - M); lsum += ev[i]; }
    red[t] = lsum; __syncthreads();
    for (int s = 128; s > 0; s >>= 1) {
        if (t < s) red[t] += red[t + s];
        __syncthreads();
    }
    float inv = 1.0f / red[0];
#pragma unroll
    for (int i = 0; i < 16; ++i) pa[n * PIX + t + 256 * i] = ev[i] * inv;
}

// ---------------- K3b: wscaled[n][co][ci] = bf16(wconv[ci][co] * ca[n][ci]) --
__global__ void wscale_kernel(const float* __restrict__ wc,
                              const float* __restrict__ ca,
                              short* __restrict__ wscaled)
{
    __shared__ float tile[32][33];
    const int n = blockIdx.z;
    const int co0 = blockIdx.x * 32, ci0 = blockIdx.y * 32;
    const int tx = threadIdx.x, ty = threadIdx.y;  // 32 x 8
#pragma unroll
    for (int r = 0; r < 4; ++r)
        tile[ty + r * 8][tx] = wc[(ci0 + ty + r * 8) * 256 + co0 + tx];
    const float cav = ca[n * 256 + ci0 + tx];      // ci = ci0+tx on the write side
    __syncthreads();
#pragma unroll
    for (int r = 0; r < 4; ++r)
        wscaled[(size_t)n * 65536 + (co0 + ty + r * 8) * 256 + ci0 + tx] =
            f2bf(tile[tx][ty + r * 8] * cav);
}

// ---------------- K4: y = leaky0.1( (bf16in @ wscaled^T) .* pa ) -------------
// Tile 64 pixels x 256 co, BK=64, 4 waves (1x4), each wave 64x64 = 4x4 MFMA.
// A and B staged via global_load_lds width=16; LDS linear, source pre-swizzled
// (slot ^= row&7 within each 128B row) so ds_read_b128 is 2-way (free).
__global__ __launch_bounds__(256, 4) void conv_mfma(
    const short* __restrict__ bf16in, const short* __restrict__ wscaled,
    const float* __restrict__ pa, float* __restrict__ out)
{
    __shared__ __attribute__((aligned(16))) short As[64 * 64];    //  8 KB
    __shared__ __attribute__((aligned(16))) short Bs[256 * 64];   // 32 KB

    const int n  = blockIdx.y;
    const int m0 = blockIdx.x * 64;     // pixel base
    const int tid = threadIdx.x;
    const int lane = tid & 63, wid = tid >> 6;
    const int l16 = lane & 15, quad = lane >> 4;
    const int l8r = lane >> 3, slot = lane & 7;

    floatx4 acc[4][4] = {};

    const short* Agb = bf16in + ((size_t)n * PIX + m0) * CH;
    const short* Bgb = wscaled + (size_t)n * 65536;

    for (int kb = 0; kb < 4; ++kb) {
        const int k0 = kb * 64;
        if (kb) __syncthreads();
        // A: 64 rows x 64 k. wave w stages rows w*16..w*16+15 (2 instrs)
#pragma unroll
        for (int i = 0; i < 2; ++i) {
            const int r = wid * 16 + i * 8 + l8r;
            gll16(Agb + (size_t)r * CH + k0 + ((slot ^ (r & 7)) << 3),
                  &As[(wid * 16 + i * 8) * 64]);
        }
        // B: 256 rows x 64 k. wave w stages rows w*64..w*64+63 (8 instrs)
#pragma unroll
        for (int i = 0; i < 8; ++i) {
            const int c = wid * 64 + i * 8 + l8r;
            gll16(Bgb + (size_t)c * CH + k0 + ((slot ^ (c & 7)) << 3),
                  &Bs[(wid * 64 + i * 8) * 64]);
        }
        __syncthreads();   // compiler drains vmcnt(0) before s_barrier
#pragma unroll
        for (int kk2 = 0; kk2 < 2; ++kk2) {
            const int sx = ((kk2 * 4 + quad) ^ (l16 & 7)) << 3;  // swizzled 16B slot
            short8 af[4], bfr[4];
#pragma unroll
            for (int mt = 0; mt < 4; ++mt)
                af[mt] = *(const short8*)&As[(mt * 16 + l16) * 64 + sx];
#pragma unroll
            for (int nt = 0; nt < 4; ++nt)
                bfr[nt] = *(const short8*)&Bs[(wid * 64 + nt * 16 + l16) * 64 + sx];
#pragma unroll
            for (int mt = 0; mt < 4; ++mt)
#pragma unroll
                for (int nt = 0; nt < 4; ++nt)
                    acc[mt][nt] = __builtin_amdgcn_mfma_f32_16x16x32_bf16(
                        af[mt], bfr[nt], acc[mt][nt], 0, 0, 0);
        }
    }

    // epilogue: z = acc * pa[pixel]; leaky 0.1; store
#pragma unroll
    for (int mt = 0; mt < 4; ++mt) {
#pragma unroll
        for (int reg = 0; reg < 4; ++reg) {
            const int pix = m0 + mt * 16 + quad * 4 + reg;
            const float pav = pa[n * PIX + pix];
            float* orow = out + ((size_t)(n * PIX + pix)) * CH + wid * 64;
#pragma unroll
            for (int nt = 0; nt < 4; ++nt) {
                float z = acc[mt][nt][reg] * pav;
                orow[nt * 16 + l16] = z > 0.f ? z : 0.1f * z;
            }
        }
    }
}

extern "C" void kernel_launch(void* const* d_in, const int* in_sizes, int n_in,
                              void* d_out, int out_size, void* d_ws, size_t ws_size,
                              hipStream_t stream) {
    const float* inputs = (const float*)d_in[0];   // [32,64,64,256]
    const float* style  = (const float*)d_in[1];   // [32,256]
    const float* wdense = (const float*)d_in[2];   // [256,256]
    const float* wconv  = (const float*)d_in[3];   // [1,1,256,256] = [ci][co]
    float* out = (float*)d_out;

    // workspace layout (bytes)
    char* ws = (char*)d_ws;
    float* q           = (float*)(ws + 0);          //  32 KB
    float* ca          = (float*)(ws + 32768);      //  32 KB
    float* pa_logits   = (float*)(ws + 65536);      // 512 KB
    float* pa          = (float*)(ws + 589824);     // 512 KB
    float* colsum_part = (float*)(ws + 1114112);    //   4 MB  [32][128][256] f32
    short* wscaled     = (short*)(ws + 5308416);    //   4 MB  [32][256][256] bf16
    short* bf16in      = (short*)(ws + 9502720);    //  64 MB  [32][4096][256] bf16

    style_kernel<<<NBATCH, 256, 0, stream>>>(style, wdense, q);
    reduce_cast_kernel<<<dim3(32, NBATCH), 256, 0, stream>>>(inputs, q, colsum_part,
                                                             pa_logits, bf16in);
    softmax_kernel<<<NBATCH, 256, 0, stream>>>(colsum_part, q, pa_logits, ca, pa);
    wscale_kernel<<<dim3(8, 8, NBATCH), dim3(32, 8), 0, stream>>>(wconv, ca, wscaled);
    conv_mfma<<<dim3(64, NBATCH), 256, 0, stream>>>(bf16in, wscaled, pa, out);
}

// Round 2
// 316.305 us; speedup vs baseline: 1.0006x; 1.0006x over previous
//
#include <hip/hip_runtime.h>

// Problem: N=32, W=64, H=64, C=256, D_STYLE=256. All fp32 in/out.
// out = leaky0.1( (inputs * softmax_c(colsum*q*s) * softmax_wh(inputs·q*s)) @ Wconv )
// 3-dispatch pipeline: ca folded into weights, inputs pre-cast to bf16, conv with
// double-buffered global_load_lds (2-phase pipeline), q computed inline per block.

#define NBATCH 32
#define PIX 4096          // 64*64
#define CH 256
#define SCALE 0.0625f     // 1/sqrt(256)

typedef __attribute__((ext_vector_type(8))) short short8;
typedef __attribute__((ext_vector_type(4))) short short4v;
typedef __attribute__((ext_vector_type(4))) float floatx4;

__device__ __forceinline__ short f2bf(float x) {
    unsigned u = __builtin_bit_cast(unsigned, x);
    u += 0x7fffu + ((u >> 16) & 1u);   // round-to-nearest-even
    return (short)(u >> 16);
}

// async global->LDS, 16B per lane; LDS dest = wave-uniform base + lane*16
__device__ __forceinline__ void gll16(const void* g, void* l) {
    __builtin_amdgcn_global_load_lds(
        (const __attribute__((address_space(1))) unsigned int*)g,
        (__attribute__((address_space(3))) unsigned int*)l, 16, 0, 0);
}

// ---------------- K_A: q inline; colsum partials; pa_logits; bf16 cast -------
__global__ __launch_bounds__(256) void reduce_cast_q(
    const float* __restrict__ inp, const float* __restrict__ style,
    const float* __restrict__ wd,
    float* __restrict__ q_out, float* __restrict__ colsum_part,
    float* __restrict__ pa_logits, short* __restrict__ bf16in)
{
    __shared__ float s[256];
    __shared__ float q_s[256];
    const int n = blockIdx.y, chunk = blockIdx.x, t = threadIdx.x;

    // q = leaky_relu(style[n] @ wd, 0.3), computed redundantly per block (wd is L2-hot)
    s[t] = style[n * 256 + t];
    __syncthreads();
    float acc = 0.f;
#pragma unroll 8
    for (int k = 0; k < 256; ++k) acc += s[k] * wd[k * 256 + t];
    acc = acc > 0.f ? acc : 0.3f * acc;
    q_s[t] = acc;
    if (chunk == 0) q_out[n * 256 + t] = acc;   // for softmax kernel
    __syncthreads();

    const int lane = t & 63, w = t >> 6;
    const float4 qv = *(const float4*)&q_s[lane * 4];
    float4 cs = make_float4(0.f, 0.f, 0.f, 0.f);
    const int pbase = chunk * 128 + w * 32;
    const float* base = inp + ((size_t)n * PIX + pbase) * CH;
    short* obase = bf16in + ((size_t)n * PIX + pbase) * CH;
#pragma unroll 4
    for (int j = 0; j < 32; ++j) {
        float4 v = *(const float4*)&base[(size_t)j * CH + lane * 4];
        float d = v.x * qv.x + v.y * qv.y + v.z * qv.z + v.w * qv.w;
        cs.x += v.x; cs.y += v.y; cs.z += v.z; cs.w += v.w;
        short4v sv;
        sv.x = f2bf(v.x); sv.y = f2bf(v.y); sv.z = f2bf(v.z); sv.w = f2bf(v.w);
        *(short4v*)&obase[(size_t)j * CH + lane * 4] = sv;
#pragma unroll
        for (int off = 32; off; off >>= 1) d += __shfl_xor(d, off);
        if (lane == 0) pa_logits[n * PIX + pbase + j] = d * SCALE;
    }
    // one partial row per wave; no atomics, no zero-init needed
    *(float4*)&colsum_part[((size_t)n * 128 + chunk * 4 + w) * 256 + lane * 4] = cs;
}

// ---------------- K_B: ca softmax; pa softmax; wscaled = bf16(diag(ca)@W)^T --
__global__ __launch_bounds__(256) void softmax_wscale(
    const float* __restrict__ colsum_part, const float* __restrict__ q,
    const float* __restrict__ pa_logits, const float* __restrict__ wc,
    float* __restrict__ pa, short* __restrict__ wscaled)
{
    __shared__ float red[256];
    __shared__ float ca_s[256];
    __shared__ float wt[32][257];   // [ci-local][co]  (257: conflict-free transpose)
    const int n = blockIdx.x, t = threadIdx.x;

    // ---- ca over 256 channels ----
    float csum = 0.f;
#pragma unroll 8
    for (int i = 0; i < 128; ++i) csum += colsum_part[((size_t)n * 128 + i) * 256 + t];
    float lg = csum * q[n * 256 + t] * SCALE;
    red[t] = lg; __syncthreads();
    for (int s = 128; s > 0; s >>= 1) {
        if (t < s) red[t] = fmaxf(red[t], red[t + s]);
        __syncthreads();
    }
    float m = red[0]; __syncthreads();
    float e = expf(lg - m);
    red[t] = e; __syncthreads();
    for (int s = 128; s > 0; s >>= 1) {
        if (t < s) red[t] += red[t + s];
        __syncthreads();
    }
    ca_s[t] = e / red[0];
    __syncthreads();

    // ---- pa over 4096 pixels ----
    float lv[16];
    float lmax = -1e30f;
#pragma unroll
    for (int i = 0; i < 16; ++i) {
        lv[i] = pa_logits[n * PIX + t + 256 * i];
        lmax = fmaxf(lmax, lv[i]);
    }
    red[t] = lmax; __syncthreads();
    for (int s = 128; s > 0; s >>= 1) {
        if (t < s) red[t] = fmaxf(red[t], red[t + s]);
        __syncthreads();
    }
    float M = red[0]; __syncthreads();
    float ev[16], lsum = 0.f;
#pragma unroll
    for (int i = 0; i < 16; ++i) { ev[i] = expf(lv[i] - M); lsum += ev[i]; }
    red[t] = lsum; __syncthreads();
    for (int s = 128; s > 0; s >>= 1) {
        if (t < s) red[t] += red[t + s];
        __syncthreads();
    }
    float inv = 1.0f / red[0];
#pragma unroll
    for (int i = 0; i < 16; ++i) pa[n * PIX + t + 256 * i] = ev[i] * inv;

    // ---- wscaled[n][co][ci] = bf16(wc[ci][co] * ca[ci]), 8 ci-strips of 32 ----
    const int tx = t & 31, ty = t >> 5;   // 32 x 8
    for (int strip = 0; strip < 8; ++strip) {
        const int ci0 = strip * 32;
        __syncthreads();
#pragma unroll
        for (int r = 0; r < 4; ++r) {
            const int ci = ty + r * 8;
#pragma unroll
            for (int cb = 0; cb < 8; ++cb)
                wt[ci][cb * 32 + tx] = wc[(ci0 + ci) * 256 + cb * 32 + tx];
        }
        __syncthreads();
        const float cav = ca_s[ci0 + tx];
#pragma unroll
        for (int r = 0; r < 4; ++r) {
#pragma unroll
            for (int cb = 0; cb < 8; ++cb) {
                const int co = cb * 32 + ty + r * 8;
                wscaled[(size_t)n * 65536 + co * 256 + ci0 + tx] =
                    f2bf(wt[tx][co] * cav);
            }
        }
    }
}

// ---------------- K_C: y = leaky0.1( (bf16in @ wscaled^T) .* pa ) ------------
// Tile 64 pixels x 256 co, BK=64, 4 waves (1x4), each wave 64x64 = 4x4 MFMA.
// Double-buffered LDS (80 KB, 2 blocks/CU): stage K-step t+1 before computing t,
// so the vmcnt(0) drain at __syncthreads lands after the compute phase.
__global__ __launch_bounds__(256, 2) void conv_mfma(
    const short* __restrict__ bf16in, const short* __restrict__ wscaled,
    const float* __restrict__ pa, float* __restrict__ out)
{
    __shared__ __attribute__((aligned(16))) short As[2][64 * 64];    // 16 KB
    __shared__ __attribute__((aligned(16))) short Bs[2][256 * 64];   // 64 KB

    const int n  = blockIdx.y;
    const int m0 = blockIdx.x * 64;     // pixel base
    const int tid = threadIdx.x;
    const int lane = tid & 63, wid = tid >> 6;
    const int l16 = lane & 15, quad = lane >> 4;
    const int l8r = lane >> 3, slot = lane & 7;

    floatx4 acc[4][4] = {};

    const short* Agb = bf16in + ((size_t)n * PIX + m0) * CH;
    const short* Bgb = wscaled + (size_t)n * 65536;

    auto stage = [&](int kb, int buf) {
        const int k0 = kb * 64;
        // A: 64 rows x 64 k. wave w stages rows w*16..w*16+15 (2 instrs)
#pragma unroll
        for (int i = 0; i < 2; ++i) {
            const int r = wid * 16 + i * 8 + l8r;
            gll16(Agb + (size_t)r * CH + k0 + ((slot ^ (r & 7)) << 3),
                  &As[buf][(wid * 16 + i * 8) * 64]);
        }
        // B: 256 rows x 64 k. wave w stages rows w*64..w*64+63 (8 instrs)
#pragma unroll
        for (int i = 0; i < 8; ++i) {
            const int c = wid * 64 + i * 8 + l8r;
            gll16(Bgb + (size_t)c * CH + k0 + ((slot ^ (c & 7)) << 3),
                  &Bs[buf][(wid * 64 + i * 8) * 64]);
        }
    };

    stage(0, 0);
    __syncthreads();                       // buf0 ready

    for (int kb = 0; kb < 4; ++kb) {
        const int cur = kb & 1;
        if (kb < 3) stage(kb + 1, cur ^ 1);   // issue next tile BEFORE compute
#pragma unroll
        for (int kk2 = 0; kk2 < 2; ++kk2) {
            const int sx = ((kk2 * 4 + quad) ^ (l16 & 7)) << 3;  // swizzled 16B slot
            short8 af[4], bfr[4];
#pragma unroll
            for (int mt = 0; mt < 4; ++mt)
                af[mt] = *(const short8*)&As[cur][(mt * 16 + l16) * 64 + sx];
#pragma unroll
            for (int nt = 0; nt < 4; ++nt)
                bfr[nt] = *(const short8*)&Bs[cur][(wid * 64 + nt * 16 + l16) * 64 + sx];
#pragma unroll
            for (int mt = 0; mt < 4; ++mt)
#pragma unroll
                for (int nt = 0; nt < 4; ++nt)
                    acc[mt][nt] = __builtin_amdgcn_mfma_f32_16x16x32_bf16(
                        af[mt], bfr[nt], acc[mt][nt], 0, 0, 0);
        }
        __syncthreads();   // drains next-tile loads (hidden under compute above)
    }

    // epilogue: z = acc * pa[pixel]; leaky 0.1; store
#pragma unroll
    for (int mt = 0; mt < 4; ++mt) {
#pragma unroll
        for (int reg = 0; reg < 4; ++reg) {
            const int pix = m0 + mt * 16 + quad * 4 + reg;
            const float pav = pa[n * PIX + pix];
            float* orow = out + ((size_t)(n * PIX + pix)) * CH + wid * 64;
#pragma unroll
            for (int nt = 0; nt < 4; ++nt) {
                float z = acc[mt][nt][reg] * pav;
                orow[nt * 16 + l16] = z > 0.f ? z : 0.1f * z;
            }
        }
    }
}

extern "C" void kernel_launch(void* const* d_in, const int* in_sizes, int n_in,
                              void* d_out, int out_size, void* d_ws, size_t ws_size,
                              hipStream_t stream) {
    const float* inputs = (const float*)d_in[0];   // [32,64,64,256]
    const float* style  = (const float*)d_in[1];   // [32,256]
    const float* wdense = (const float*)d_in[2];   // [256,256]
    const float* wconv  = (const float*)d_in[3];   // [1,1,256,256] = [ci][co]
    float* out = (float*)d_out;

    // workspace layout (bytes)
    char* ws = (char*)d_ws;
    float* q           = (float*)(ws + 0);          //  32 KB
    float* pa_logits   = (float*)(ws + 32768);      // 512 KB
    float* pa          = (float*)(ws + 557056);     // 512 KB
    float* colsum_part = (float*)(ws + 1081344);    //   4 MB  [32][128][256] f32
    short* wscaled     = (short*)(ws + 5275648);    //   4 MB  [32][256][256] bf16
    short* bf16in      = (short*)(ws + 9469952);    //  64 MB  [32][4096][256] bf16

    reduce_cast_q<<<dim3(32, NBATCH), 256, 0, stream>>>(inputs, style, wdense, q,
                                                        colsum_part, pa_logits, bf16in);
    softmax_wscale<<<NBATCH, 256, 0, stream>>>(colsum_part, q, pa_logits, wconv,
                                               pa, wscaled);
    conv_mfma<<<dim3(64, NBATCH), 256, 0, stream>>>(bf16in, wscaled, pa, out);
}

// Round 3
// 311.460 us; speedup vs baseline: 1.0162x; 1.0156x over previous
//
#include <hip/hip_runtime.h>

// Problem: N=32, W=64, H=64, C=256, D_STYLE=256. All fp32 in/out.
// out = leaky0.1( (inputs * softmax_c(colsum*q*s) * softmax_wh(inputs·q*s)) @ Wconv )
// 4-dispatch pipeline: style -> reduce_cast (streaming, LDS-transpose reduce)
// -> softmax_wscale (1024 thr, wave reductions) -> conv (BK=32 dbuf, 4 blk/CU).

#define NBATCH 32
#define PIX 4096          // 64*64
#define CH 256
#define SCALE 0.0625f     // 1/sqrt(256)

typedef __attribute__((ext_vector_type(8))) short short8;
typedef __attribute__((ext_vector_type(4))) short short4v;
typedef __attribute__((ext_vector_type(4))) float floatx4;

__device__ __forceinline__ short f2bf(float x) {
    unsigned u = __builtin_bit_cast(unsigned, x);
    u += 0x7fffu + ((u >> 16) & 1u);   // round-to-nearest-even
    return (short)(u >> 16);
}

// async global->LDS, 16B per lane; LDS dest = wave-uniform base + lane*16
__device__ __forceinline__ void gll16(const void* g, void* l) {
    __builtin_amdgcn_global_load_lds(
        (const __attribute__((address_space(1))) unsigned int*)g,
        (__attribute__((address_space(3))) unsigned int*)l, 16, 0, 0);
}

// ---------------- K1: q = leaky_relu(style @ w_dense, 0.3) -------------------
__global__ __launch_bounds__(256) void style_kernel(
    const float* __restrict__ style, const float* __restrict__ wd,
    float* __restrict__ q)
{
    __shared__ float s[256];
    const int n = blockIdx.x, t = threadIdx.x;
    s[t] = style[n * 256 + t];
    __syncthreads();
    float acc = 0.f;
#pragma unroll 8
    for (int k = 0; k < 256; ++k) acc += s[k] * wd[k * 256 + t];
    q[n * 256 + t] = acc > 0.f ? acc : 0.3f * acc;
}

// ---------------- K2: streaming pass: colsum partials, pa_logits, bf16 cast --
// No cross-lane chains in the stream loop: per-lane dot partial goes to LDS,
// bulk-reduced after the loop (pad 67 -> 2-way bank conflicts = free).
__global__ __launch_bounds__(256) void reduce_cast(
    const float* __restrict__ inp, const float* __restrict__ q,
    float* __restrict__ colsum_part, float* __restrict__ pa_logits,
    short* __restrict__ bf16in)
{
    __shared__ float part[4][32][67];   // [wave][pixel][lane] f32, 34.3 KB
    const int n = blockIdx.y, chunk = blockIdx.x;
    const int t = threadIdx.x, lane = t & 63, w = t >> 6;
    const float4 qv = *(const float4*)&q[n * 256 + lane * 4];
    float4 cs = make_float4(0.f, 0.f, 0.f, 0.f);
    const int pbase = chunk * 128 + w * 32;
    const float* base = inp + ((size_t)n * PIX + pbase) * CH;
    short* obase = bf16in + ((size_t)n * PIX + pbase) * CH;
#pragma unroll 4
    for (int j = 0; j < 32; ++j) {
        float4 v = *(const float4*)&base[(size_t)j * CH + lane * 4];
        cs.x += v.x; cs.y += v.y; cs.z += v.z; cs.w += v.w;
        part[w][j][lane] = v.x * qv.x + v.y * qv.y + v.z * qv.z + v.w * qv.w;
        short4v sv;
        sv.x = f2bf(v.x); sv.y = f2bf(v.y); sv.z = f2bf(v.z); sv.w = f2bf(v.w);
        *(short4v*)&obase[(size_t)j * CH + lane * 4] = sv;
    }
    __syncthreads();
    // lane (l&31, l>>5) sums 32 consecutive partials of pixel l&31
    const int p = lane & 31, seg = lane >> 5;
    float s0 = 0.f, s1 = 0.f, s2 = 0.f, s3 = 0.f;
#pragma unroll
    for (int i = 0; i < 8; ++i) {
        s0 += part[w][p][seg * 32 + i * 4 + 0];
        s1 += part[w][p][seg * 32 + i * 4 + 1];
        s2 += part[w][p][seg * 32 + i * 4 + 2];
        s3 += part[w][p][seg * 32 + i * 4 + 3];
    }
    float sum = (s0 + s1) + (s2 + s3);
    sum += __shfl_xor(sum, 32);
    if (lane < 32) pa_logits[n * PIX + pbase + lane] = sum * SCALE;
    *(float4*)&colsum_part[((size_t)n * 128 + chunk * 4 + w) * 256 + lane * 4] = cs;
}

// ---------------- K3: ca softmax; pa softmax; wscaled = bf16(diag(ca)@W)^T --
// 1024 threads, wave-level shfl reductions + 16-entry LDS combine.
__global__ __launch_bounds__(1024) void softmax_wscale(
    const float* __restrict__ colsum_part, const float* __restrict__ q,
    const float* __restrict__ pa_logits, const float* __restrict__ wc,
    float* __restrict__ pa, short* __restrict__ wscaled)
{
    __shared__ float red4[4][256];
    __shared__ float wred[16];
    __shared__ float ca_s[256];
    __shared__ float wt[32][257];
    const int n = blockIdx.x, t = threadIdx.x;
    const int lane = t & 63, wave = t >> 6;

    // ---- colsum: thread (seg, ch) sums 32 of 128 partial rows ----
    {
        const int ch = t & 255, seg = t >> 8;
        float c0 = 0.f;
#pragma unroll 8
        for (int i = 0; i < 32; ++i)
            c0 += colsum_part[((size_t)n * 128 + seg * 32 + i) * 256 + ch];
        red4[seg][ch] = c0;
    }
    __syncthreads();

    // ---- ca over 256 channels (threads 0..255 hold data) ----
    float lg = -1e30f, e = 0.f;
    if (t < 256) {
        float csum = red4[0][t] + red4[1][t] + red4[2][t] + red4[3][t];
        lg = csum * q[n * 256 + t] * SCALE;
    }
    float m = lg;
#pragma unroll
    for (int off = 32; off; off >>= 1) m = fmaxf(m, __shfl_xor(m, off));
    if (lane == 0) wred[wave] = m;
    __syncthreads();
    m = fmaxf(fmaxf(wred[0], wred[1]), fmaxf(wred[2], wred[3]));
    if (t < 256) e = expf(lg - m);
    float es = e;
#pragma unroll
    for (int off = 32; off; off >>= 1) es += __shfl_xor(es, off);
    __syncthreads();
    if (lane == 0) wred[wave] = es;
    __syncthreads();
    float S = wred[0] + wred[1] + wred[2] + wred[3];
    if (t < 256) ca_s[t] = e / S;

    // ---- pa over 4096 pixels, 4 per thread ----
    float lv[4], lmax = -1e30f;
#pragma unroll
    for (int i = 0; i < 4; ++i) {
        lv[i] = pa_logits[n * PIX + t + 1024 * i];
        lmax = fmaxf(lmax, lv[i]);
    }
#pragma unroll
    for (int off = 32; off; off >>= 1) lmax = fmaxf(lmax, __shfl_xor(lmax, off));
    __syncthreads();
    if (lane == 0) wred[wave] = lmax;
    __syncthreads();
    float M = wred[0];
#pragma unroll
    for (int i = 1; i < 16; ++i) M = fmaxf(M, wred[i]);
    float ev[4], lsum = 0.f;
#pragma unroll
    for (int i = 0; i < 4; ++i) { ev[i] = expf(lv[i] - M); lsum += ev[i]; }
#pragma unroll
    for (int off = 32; off; off >>= 1) lsum += __shfl_xor(lsum, off);
    __syncthreads();
    if (lane == 0) wred[wave] = lsum;
    __syncthreads();
    float Ssum = 0.f;
#pragma unroll
    for (int i = 0; i < 16; ++i) Ssum += wred[i];
    float inv = 1.0f / Ssum;
#pragma unroll
    for (int i = 0; i < 4; ++i) pa[n * PIX + t + 1024 * i] = ev[i] * inv;

    // ---- wscaled[n][co][ci] = bf16(wc[ci][co] * ca[ci]), 8 ci-strips of 32 --
    const int tx = t & 31;
    for (int strip = 0; strip < 8; ++strip) {
        const int ci0 = strip * 32;
        __syncthreads();
#pragma unroll
        for (int r = 0; r < 8; ++r) {
            const int idx = t + 1024 * r;               // 8192 elems / strip
            wt[idx >> 8][idx & 255] = wc[(ci0 + (idx >> 8)) * 256 + (idx & 255)];
        }
        __syncthreads();
        const float cav = ca_s[ci0 + tx];
#pragma unroll
        for (int r = 0; r < 8; ++r) {
            const int co = r * 32 + (t >> 5);
            wscaled[(size_t)n * 65536 + co * 256 + ci0 + tx] = f2bf(wt[tx][co] * cav);
        }
    }
}

// ---------------- K4: y = leaky0.1( (bf16in @ wscaled^T) .* pa ) ------------
// Tile 64 pixels x 256 co, BK=32 double-buffered: LDS 40 KB -> 4 blocks/CU
// (16 waves/CU). Swizzle: slot ^= (row>>1)&3 -> 2-way conflicts (free) on
// both the linear gll16 stage (pre-swizzled source) and the ds_read_b128.
__global__ __launch_bounds__(256, 4) void conv_mfma(
    const short* __restrict__ bf16in, const short* __restrict__ wscaled,
    const float* __restrict__ pa, float* __restrict__ out)
{
    __shared__ __attribute__((aligned(16))) short As[2][64 * 32];    //  8 KB
    __shared__ __attribute__((aligned(16))) short Bs[2][256 * 32];   // 32 KB

    const int n  = blockIdx.y;
    const int m0 = blockIdx.x * 64;     // pixel base
    const int tid = threadIdx.x;
    const int lane = tid & 63, wid = tid >> 6;
    const int l16 = lane & 15, quad = lane >> 4;
    const int r4 = lane >> 2, s4 = lane & 3;   // staging: row-in-16, 16B slot

    floatx4 acc[4][4] = {};

    const short* Agb = bf16in + ((size_t)n * PIX + m0) * CH;
    const short* Bgb = wscaled + (size_t)n * 65536;

    auto stage = [&](int kb, int buf) {
        const int k0 = kb * 32;
        // A: 64 rows x 32 k = 4 KB; 1 instr per wave covers 16 rows
        {
            const int r = wid * 16 + r4;
            gll16(Agb + (size_t)r * CH + k0 + ((s4 ^ ((r >> 1) & 3)) << 3),
                  &As[buf][(wid * 16) * 32]);
        }
        // B: 256 rows x 32 k = 16 KB; 4 instrs per wave
#pragma unroll
        for (int i = 0; i < 4; ++i) {
            const int c = wid * 64 + i * 16 + r4;
            gll16(Bgb + (size_t)c * CH + k0 + ((s4 ^ ((c >> 1) & 3)) << 3),
                  &Bs[buf][(wid * 64 + i * 16) * 32]);
        }
    };

    stage(0, 0);
    __syncthreads();                       // buf0 ready

    for (int kb = 0; kb < 8; ++kb) {
        const int cur = kb & 1;
        if (kb < 7) stage(kb + 1, cur ^ 1);   // issue next tile BEFORE compute
        short8 af[4], bfr[4];
#pragma unroll
        for (int mt = 0; mt < 4; ++mt) {
            const int row = mt * 16 + l16;
            af[mt] = *(const short8*)&As[cur][row * 32 + ((quad ^ ((row >> 1) & 3)) << 3)];
        }
#pragma unroll
        for (int nt = 0; nt < 4; ++nt) {
            const int row = wid * 64 + nt * 16 + l16;
            bfr[nt] = *(const short8*)&Bs[cur][row * 32 + ((quad ^ ((row >> 1) & 3)) << 3)];
        }
#pragma unroll
        for (int mt = 0; mt < 4; ++mt)
#pragma unroll
            for (int nt = 0; nt < 4; ++nt)
                acc[mt][nt] = __builtin_amdgcn_mfma_f32_16x16x32_bf16(
                    af[mt], bfr[nt], acc[mt][nt], 0, 0, 0);
        __syncthreads();   // drains next-tile loads (issued before compute)
    }

    // epilogue: z = acc * pa[pixel]; leaky 0.1; store
#pragma unroll
    for (int mt = 0; mt < 4; ++mt) {
#pragma unroll
        for (int reg = 0; reg < 4; ++reg) {
            const int pix = m0 + mt * 16 + quad * 4 + reg;
            const float pav = pa[n * PIX + pix];
            float* orow = out + ((size_t)(n * PIX + pix)) * CH + wid * 64;
#pragma unroll
            for (int nt = 0; nt < 4; ++nt) {
                float z = acc[mt][nt][reg] * pav;
                orow[nt * 16 + l16] = z > 0.f ? z : 0.1f * z;
            }
        }
    }
}

extern "C" void kernel_launch(void* const* d_in, const int* in_sizes, int n_in,
                              void* d_out, int out_size, void* d_ws, size_t ws_size,
                              hipStream_t stream) {
    const float* inputs = (const float*)d_in[0];   // [32,64,64,256]
    const float* style  = (const float*)d_in[1];   // [32,256]
    const float* wdense = (const float*)d_in[2];   // [256,256]
    const float* wconv  = (const float*)d_in[3];   // [1,1,256,256] = [ci][co]
    float* out = (float*)d_out;

    // workspace layout (bytes)
    char* ws = (char*)d_ws;
    float* q           = (float*)(ws + 0);          //  32 KB
    float* pa_logits   = (float*)(ws + 32768);      // 512 KB
    float* pa          = (float*)(ws + 557056);     // 512 KB
    float* colsum_part = (float*)(ws + 1081344);    //   4 MB  [32][128][256] f32
    short* wscaled     = (short*)(ws + 5275648);    //   4 MB  [32][256][256] bf16
    short* bf16in      = (short*)(ws + 9469952);    //  64 MB  [32][4096][256] bf16

    style_kernel<<<NBATCH, 256, 0, stream>>>(style, wdense, q);
    reduce_cast<<<dim3(32, NBATCH), 256, 0, stream>>>(inputs, q, colsum_part,
                                                      pa_logits, bf16in);
    softmax_wscale<<<NBATCH, 1024, 0, stream>>>(colsum_part, q, pa_logits, wconv,
                                                pa, wscaled);
    conv_mfma<<<dim3(64, NBATCH), 256, 0, stream>>>(bf16in, wscaled, pa, out);
}